// Round 2
// baseline (470.893 us; speedup 1.0000x reference)
//
#include <hip/hip_runtime.h>
#include <stdint.h>

typedef unsigned short u16;
typedef unsigned int   u32;

typedef __bf16 bf16x8 __attribute__((ext_vector_type(8)));
typedef float  f32x4  __attribute__((ext_vector_type(4)));

__device__ __forceinline__ float bf2f(u16 h) {
    return __uint_as_float(((u32)h) << 16);
}
__device__ __forceinline__ u16 f2bf(float f) {
    u32 u = __float_as_uint(f);
    u += 0x7FFFu + ((u >> 16) & 1u);   // RNE
    return (u16)(u >> 16);
}

#define GLOAD_LDS16(g, l)                                                     \
    __builtin_amdgcn_global_load_lds(                                         \
        (const __attribute__((address_space(1))) void*)(g),                   \
        (__attribute__((address_space(3))) void*)(l), 16, 0, 0)

// ---------------------------------------------------------------------------
// f32 -> bf16 bulk convert, 8 elems/thread
// ---------------------------------------------------------------------------
__global__ __launch_bounds__(256) void cvt_f32_bf16(const float* __restrict__ in,
                                                    u16* __restrict__ out) {
    int i = blockIdx.x * 256 + threadIdx.x;
    const float4* p = (const float4*)in + (size_t)i * 2;
    float4 a = p[0], b = p[1];
    union { u16 s[8]; uint4 v; } o;
    o.s[0] = f2bf(a.x); o.s[1] = f2bf(a.y); o.s[2] = f2bf(a.z); o.s[3] = f2bf(a.w);
    o.s[4] = f2bf(b.x); o.s[5] = f2bf(b.y); o.s[6] = f2bf(b.z); o.s[7] = f2bf(b.w);
    ((uint4*)out)[i] = o.v;
}

// ---------------------------------------------------------------------------
// Transpose+convert W[R][Cc] (f32) -> Wt[Cc][R] (bf16), dims multiple of 32
// ---------------------------------------------------------------------------
__global__ void transpose_cvt(const float* __restrict__ in, u16* __restrict__ out,
                              int R, int Cc) {
    __shared__ float tile[32][33];
    int c0 = blockIdx.x * 32, r0 = blockIdx.y * 32;
    int tx = threadIdx.x, ty = threadIdx.y;
    tile[ty][tx] = in[(size_t)(r0 + ty) * Cc + c0 + tx];
    __syncthreads();
    out[(size_t)(c0 + ty) * R + r0 + tx] = f2bf(tile[tx][ty]);
}

// ---------------------------------------------------------------------------
// Precompute bias+mask, swizzled to the MFMA C-fragment access pattern:
// biasL[cls][h][mi][ni][quad][l16][r] (float4 over r).
// ---------------------------------------------------------------------------
__global__ __launch_bounds__(64) void build_bias(const float* __restrict__ table,
                                                 float* __restrict__ biasL) {
    int cls = blockIdx.x >> 4;
    int h   = blockIdx.x & 15;
    int lane = threadIdx.x;
    int quad = lane >> 4, l16 = lane & 15;
    int eh = cls >> 1, ew = cls & 1;
    float* base = biasL + (size_t)(cls * 16 + h) * 4096;
#pragma unroll
    for (int mi = 0; mi < 4; mi++) {
#pragma unroll
        for (int ni = 0; ni < 4; ni++) {
            float4 v;
            float* vp = &v.x;
#pragma unroll
            for (int r = 0; r < 4; r++) {
                int m = mi * 16 + quad * 4 + r;
                int c = ni * 16 + l16;
                float b;
                if (c >= 49)      b = -1e9f;
                else if (m >= 49) b = 0.f;
                else {
                    int ty = m / 7, tx = m % 7, jy = c / 7, jx = c % 7;
                    b = table[((ty - jy + 6) * 13 + (tx - jx + 6)) * 16 + h];
                    int ridr = (eh ? (ty < 4 ? 1 : 2) : 0) * 3 + (ew ? (tx < 4 ? 1 : 2) : 0);
                    int ridc = (eh ? (jy < 4 ? 1 : 2) : 0) * 3 + (ew ? (jx < 4 ? 1 : 2) : 0);
                    if (ridr != ridc) b -= 100.f;
                }
                vp[r] = b;
            }
            ((float4*)base)[((mi * 4 + ni) * 4 + quad) * 16 + l16] = v;
        }
    }
}

// ---------------------------------------------------------------------------
// 128x256 2-phase GEMM: C[M][N] = A[M][K] @ Bt[N][K]^T + bias[N] (+ res).
// 512 threads = 8 waves (2M x 4N), per-wave 64x64 output, BK=64.
// LDS 96 KiB double-buffered (A 2x16K, B 2x32K); XOR bank swizzle via
// inverse-permuted global_load_lds SOURCE + swizzled ds_read address.
// 2 phases/K-tile (4 barriers). Staging: ph1 -> {A(kt+1), B-half1(kt+1)}
// into other buffer; ph2 -> {B-half0(kt+2)} into current buffer (its reads
// drained at ph1's lgkm+barrier). vmcnt(2) per K-tile keeps 2 loads in
// flight across the barrier; vmcnt(0) only in the tail. setprio around
// MFMA clusters. XCD-aware blockIdx swizzle (grid % 8 == 0).
// ---------------------------------------------------------------------------
template <bool OUT_F32>
__global__ __launch_bounds__(512, 2) void gemm128(
    const u16* __restrict__ A, const u16* __restrict__ Bt,
    const float* __restrict__ bias, const float* __restrict__ res,
    void* __restrict__ Cout, int M, int N, int K, int GX)
{
    __shared__ __align__(16) char smem[98304];
    char* AsB = smem;            // 2 bufs x 128 rows x 128 B = 32 KiB
    char* BsB = smem + 32768;    // 2 bufs x 256 rows x 128 B = 64 KiB

    // ---- XCD-aware swizzle (bijective: gridDim.x % 8 == 0) ----
    const int nwg = (int)gridDim.x;
    int wg = (int)blockIdx.x;
    wg = (wg & 7) * (nwg >> 3) + (wg >> 3);
    const int bx = wg % GX;
    const int by = wg / GX;
    const size_t m0 = (size_t)by * 128;
    const size_t n0 = (size_t)bx * 256;

    const int t    = threadIdx.x;
    const int lane = t & 63;
    const int w    = t >> 6;
    const int wm   = w >> 2, wn = w & 3;
    const int quad = lane >> 4, l16 = lane & 15;
    const int xr   = l16 & 7;
    const int cb   = (quad ^ xr) * 16;       // swizzled 16B chunk base (ks=0)

    // ---- staging geometry: thread t covers row r0, 16B slot s8 ----
    const int r0  = t >> 3;                  // 0..63
    const int s8  = t & 7;
    const int swz = (s8 ^ (r0 & 7)) * 8;     // inverse-permuted source chunk
    const u16* Ag0 = A  + (m0 + r0) * K + swz;
    const u16* Bg0 = Bt + (n0 + r0) * K + swz;
    const size_t j64K = (size_t)64 * K;

    auto stageA = [&](int bf, int half, int ktt) {   // 64 rows, 1 load/thread
        char* d = AsB + bf * 16384 + half * 8192 + t * 16;
        GLOAD_LDS16(Ag0 + (size_t)half * j64K + ktt * 64, d);
    };
    auto stageB = [&](int bf, int half, int ktt) {   // 128 rows, 2 loads/thread
        char* d = BsB + bf * 32768 + half * 16384;
        const u16* g = Bg0 + (size_t)half * 128 * K + ktt * 64;
        GLOAD_LDS16(g, d + t * 16);
        GLOAD_LDS16(g + j64K, d + t * 16 + 8192);
    };

    f32x4 acc[4][4];
    const f32x4 fz = {0.f, 0.f, 0.f, 0.f};
#pragma unroll
    for (int i = 0; i < 4; i++)
#pragma unroll
        for (int j = 0; j < 4; j++) acc[i][j] = fz;

    const int NT = K >> 6;

    // ---- prologue: tile 0 complete + B-half0 of tile 1 (stays in flight) ----
    stageA(0, 0, 0); stageA(0, 1, 0); stageB(0, 0, 0); stageB(0, 1, 0);
    stageB(1, 0, 1);
    asm volatile("s_waitcnt vmcnt(2)" ::: "memory");   // tile 0 landed
    __builtin_amdgcn_s_barrier();

    for (int kt = 0; kt < NT; ++kt) {
        const int buf = kt & 1, nb = buf ^ 1;
        const char* Ab  = AsB + buf * 16384 + wm * 8192 + l16 * 128;
        const char* Bb  = BsB + buf * 32768 + wn * 8192 + l16 * 128;
        const char* pA0 = Ab + cb;
        const char* pA1 = Ab + (cb ^ 64);
        const char* pB0 = Bb + cb;
        const char* pB1 = Bb + (cb ^ 64);

        bf16x8 a[4][2], b[2][2];

        // ================= phase 1: nj 0..1 =================
#pragma unroll
        for (int mi = 0; mi < 4; mi++) {
            a[mi][0] = *(const bf16x8*)(pA0 + mi * 2048);
            a[mi][1] = *(const bf16x8*)(pA1 + mi * 2048);
        }
#pragma unroll
        for (int nj = 0; nj < 2; nj++) {
            b[nj][0] = *(const bf16x8*)(pB0 + nj * 2048);
            b[nj][1] = *(const bf16x8*)(pB1 + nj * 2048);
        }
        if (kt + 1 < NT) {               // into other buf: reads drained last iter
            stageA(nb, 0, kt + 1);
            stageA(nb, 1, kt + 1);
            stageB(nb, 1, kt + 1);
        }
        __builtin_amdgcn_s_barrier();
        asm volatile("s_waitcnt lgkmcnt(0)" ::: "memory");
        __builtin_amdgcn_s_setprio(1);
#pragma unroll
        for (int mi = 0; mi < 4; mi++)
#pragma unroll
            for (int nj = 0; nj < 2; nj++) {
                acc[mi][nj] = __builtin_amdgcn_mfma_f32_16x16x32_bf16(
                    a[mi][0], b[nj][0], acc[mi][nj], 0, 0, 0);
                acc[mi][nj] = __builtin_amdgcn_mfma_f32_16x16x32_bf16(
                    a[mi][1], b[nj][1], acc[mi][nj], 0, 0, 0);
            }
        __builtin_amdgcn_s_setprio(0);
        __builtin_amdgcn_s_barrier();

        // ================= phase 2: nj 2..3 =================
#pragma unroll
        for (int nj = 0; nj < 2; nj++) {
            b[nj][0] = *(const bf16x8*)(pB0 + 4096 + nj * 2048);
            b[nj][1] = *(const bf16x8*)(pB1 + 4096 + nj * 2048);
        }
        if (kt + 2 < NT) stageB(buf, 0, kt + 2);   // b0-reads drained at ph1
        __builtin_amdgcn_s_barrier();
        asm volatile("s_waitcnt lgkmcnt(0)" ::: "memory");
        __builtin_amdgcn_s_setprio(1);
#pragma unroll
        for (int mi = 0; mi < 4; mi++)
#pragma unroll
            for (int nj = 0; nj < 2; nj++) {
                acc[mi][2 + nj] = __builtin_amdgcn_mfma_f32_16x16x32_bf16(
                    a[mi][0], b[nj][0], acc[mi][2 + nj], 0, 0, 0);
                acc[mi][2 + nj] = __builtin_amdgcn_mfma_f32_16x16x32_bf16(
                    a[mi][1], b[nj][1], acc[mi][2 + nj], 0, 0, 0);
            }
        __builtin_amdgcn_s_setprio(0);
        // counted wait: tile kt+1 fully landed; B-half0(kt+2) stays in flight
        if (kt + 2 < NT) asm volatile("s_waitcnt vmcnt(2)" ::: "memory");
        else             asm volatile("s_waitcnt vmcnt(0)" ::: "memory");
        __builtin_amdgcn_s_barrier();
    }

    // ---- epilogue: per-wave LDS transpose -> vectorized stores ----
    // (lgkmcnt-only waits: do NOT drain global stores each step)
    float* scr = (float*)(void*)smem + w * 1088;   // [16][68] f32 per wave
    float bv[4];
#pragma unroll
    for (int nj = 0; nj < 4; nj++)
        bv[nj] = bias[n0 + wn * 64 + nj * 16 + l16];

    const size_t colb = n0 + wn * 64 + quad * 16;
#pragma unroll
    for (int mi = 0; mi < 4; mi++) {
#pragma unroll
        for (int nj = 0; nj < 4; nj++)
#pragma unroll
            for (int r = 0; r < 4; r++)
                scr[(quad * 4 + r) * 68 + nj * 16 + l16] = acc[mi][nj][r] + bv[nj];
        asm volatile("s_waitcnt lgkmcnt(0)" ::: "memory");  // ds writes done

        const size_t row = m0 + wm * 64 + mi * 16 + l16;
        const float4* sp = (const float4*)(scr + l16 * 68 + quad * 16);
        float4 v0 = sp[0], v1 = sp[1], v2 = sp[2], v3 = sp[3];

        if (OUT_F32) {
            const float4* rp = (const float4*)(res + row * N + colb);
            float4 r0v = rp[0], r1v = rp[1], r2v = rp[2], r3v = rp[3];
            v0.x += r0v.x; v0.y += r0v.y; v0.z += r0v.z; v0.w += r0v.w;
            v1.x += r1v.x; v1.y += r1v.y; v1.z += r1v.z; v1.w += r1v.w;
            v2.x += r2v.x; v2.y += r2v.y; v2.z += r2v.z; v2.w += r2v.w;
            v3.x += r3v.x; v3.y += r3v.y; v3.z += r3v.z; v3.w += r3v.w;
            float4* op = (float4*)((float*)Cout + row * N + colb);
            op[0] = v0; op[1] = v1; op[2] = v2; op[3] = v3;
        } else {
            union { u16 s[8]; uint4 q; } p0, p1;
            p0.s[0] = f2bf(v0.x); p0.s[1] = f2bf(v0.y); p0.s[2] = f2bf(v0.z); p0.s[3] = f2bf(v0.w);
            p0.s[4] = f2bf(v1.x); p0.s[5] = f2bf(v1.y); p0.s[6] = f2bf(v1.z); p0.s[7] = f2bf(v1.w);
            p1.s[0] = f2bf(v2.x); p1.s[1] = f2bf(v2.y); p1.s[2] = f2bf(v2.z); p1.s[3] = f2bf(v2.w);
            p1.s[4] = f2bf(v3.x); p1.s[5] = f2bf(v3.y); p1.s[6] = f2bf(v3.z); p1.s[7] = f2bf(v3.w);
            uint4* op = (uint4*)((u16*)Cout + row * N + colb);
            op[0] = p0.q; op[1] = p1.q;
        }
        asm volatile("s_waitcnt lgkmcnt(0)" ::: "memory");  // scratch reads done
    }
}

// ---------------------------------------------------------------------------
// Attention v3: 1 wave per (window, head). Unchanged this round.
// ---------------------------------------------------------------------------
__global__ __launch_bounds__(64) void attn_kernel(
    const u16* __restrict__ qkv, const float* __restrict__ biasL,
    u16* __restrict__ O)
{
    __shared__ __align__(16) u16 Ps[64 * 72];   // 9216 B
    __shared__ __align__(16) u16 Vts[32 * 72];  // 4608 B

    const int wid = blockIdx.x >> 4;
    const int h   = blockIdx.x & 15;
    const int b   = wid >> 6;
    const int wy  = (wid >> 3) & 7;
    const int wx  = wid & 7;
    const int cls = ((wy == 7) ? 2 : 0) + ((wx == 7) ? 1 : 0);
    const int lane = threadIdx.x;
    const int quad = lane >> 4, l16 = lane & 15;

    auto tokOf = [&](int m) -> size_t {
        int tt = m < 49 ? m : 48;
        int ty = tt / 7, tx = tt - ty * 7;
        int ho = wy * 7 + ty + 3; if (ho >= 56) ho -= 56;
        int wo = wx * 7 + tx + 3; if (wo >= 56) wo -= 56;
        return ((size_t)b * 56 + ho) * 56 + wo;
    };

    {
        size_t tok = tokOf(lane);
        const uint4* vs = (const uint4*)(qkv + tok * 1536 + 1024 + h * 32);
        union { uint4 u4[4]; u16 s[32]; } vb;
        vb.u4[0] = vs[0]; vb.u4[1] = vs[1]; vb.u4[2] = vs[2]; vb.u4[3] = vs[3];
#pragma unroll
        for (int d = 0; d < 32; d++) Vts[d * 72 + lane] = vb.s[d];
    }

    bf16x8 aq[4], bk[4];
#pragma unroll
    for (int i = 0; i < 4; i++) {
        size_t tok = tokOf(i * 16 + l16);
        const u16* base = qkv + tok * 1536 + h * 32 + quad * 8;
        aq[i] = *(const bf16x8*)base;
        bk[i] = *(const bf16x8*)(base + 512);
    }

    f32x4 acc[4][4];
    {
        const f32x4 fzz = {0.f, 0.f, 0.f, 0.f};
#pragma unroll
        for (int mi = 0; mi < 4; mi++)
#pragma unroll
            for (int ni = 0; ni < 4; ni++)
                acc[mi][ni] = __builtin_amdgcn_mfma_f32_16x16x32_bf16(
                    aq[mi], bk[ni], fzz, 0, 0, 0);
    }

    {
        const float scale = 0.17677669529663687f;  // 1/sqrt(32)
        const float* bp = biasL + (size_t)(cls * 16 + h) * 4096;
#pragma unroll
        for (int mi = 0; mi < 4; mi++)
#pragma unroll
            for (int ni = 0; ni < 4; ni++) {
                float4 bvv = ((const float4*)bp)[((mi * 4 + ni) * 4 + quad) * 16 + l16];
                const float* bvp = &bvv.x;
#pragma unroll
                for (int r = 0; r < 4; r++)
                    acc[mi][ni][r] = acc[mi][ni][r] * scale + bvp[r];
            }
    }

    float rinv[4][4];
    {
#pragma unroll
        for (int mi = 0; mi < 4; mi++)
#pragma unroll
            for (int r = 0; r < 4; r++) {
                float m0 = fmaxf(fmaxf(acc[mi][0][r], acc[mi][1][r]),
                                 fmaxf(acc[mi][2][r], acc[mi][3][r]));
                m0 = fmaxf(m0, __shfl_xor(m0, 1, 64));
                m0 = fmaxf(m0, __shfl_xor(m0, 2, 64));
                m0 = fmaxf(m0, __shfl_xor(m0, 4, 64));
                m0 = fmaxf(m0, __shfl_xor(m0, 8, 64));
                float e0 = __expf(acc[mi][0][r] - m0);
                float e1 = __expf(acc[mi][1][r] - m0);
                float e2 = __expf(acc[mi][2][r] - m0);
                float e3 = __expf(acc[mi][3][r] - m0);
                acc[mi][0][r] = e0; acc[mi][1][r] = e1;
                acc[mi][2][r] = e2; acc[mi][3][r] = e3;
                float s0 = (e0 + e1) + (e2 + e3);
                s0 += __shfl_xor(s0, 1, 64);
                s0 += __shfl_xor(s0, 2, 64);
                s0 += __shfl_xor(s0, 4, 64);
                s0 += __shfl_xor(s0, 8, 64);
                rinv[mi][r] = __builtin_amdgcn_rcpf(s0);
            }
    }

#pragma unroll
    for (int mi = 0; mi < 4; mi++)
#pragma unroll
        for (int ni = 0; ni < 4; ni++)
#pragma unroll
            for (int r = 0; r < 4; r++)
                Ps[(mi * 16 + quad * 4 + r) * 72 + ni * 16 + l16] =
                    f2bf(acc[mi][ni][r]);
    __syncthreads();

#pragma unroll
    for (int mi = 0; mi < 4; mi++) {
        f32x4 c0 = {0.f, 0.f, 0.f, 0.f}, c1 = {0.f, 0.f, 0.f, 0.f};
#pragma unroll
        for (int ks = 0; ks < 2; ks++) {
            bf16x8 a = *(const bf16x8*)(Ps + (mi * 16 + l16) * 72 + ks * 32 + quad * 8);
            bf16x8 b0 = *(const bf16x8*)(Vts + l16 * 72 + ks * 32 + quad * 8);
            bf16x8 b1 = *(const bf16x8*)(Vts + (16 + l16) * 72 + ks * 32 + quad * 8);
            c0 = __builtin_amdgcn_mfma_f32_16x16x32_bf16(a, b0, c0, 0, 0, 0);
            c1 = __builtin_amdgcn_mfma_f32_16x16x32_bf16(a, b1, c1, 0, 0, 0);
        }
#pragma unroll
        for (int r = 0; r < 4; r++) {
            int m = mi * 16 + quad * 4 + r;
            if (m < 49) {
                int ty = m / 7, tx = m - ty * 7;
                int ho = wy * 7 + ty + 3; if (ho >= 56) ho -= 56;
                int wo = wx * 7 + tx + 3; if (wo >= 56) wo -= 56;
                size_t tok = ((size_t)b * 56 + ho) * 56 + wo;
                u16* op = O + tok * 512 + h * 32 + l16;
                op[0]  = f2bf(c0[r] * rinv[mi][r]);
                op[16] = f2bf(c1[r] * rinv[mi][r]);
            }
        }
    }
}

// ---------------------------------------------------------------------------
extern "C" void kernel_launch(void* const* d_in, const int* in_sizes, int n_in,
                              void* d_out, int out_size, void* d_ws, size_t ws_size,
                              hipStream_t stream)
{
    const float* x      = (const float*)d_in[0];
    const float* qkv_w  = (const float*)d_in[1];
    const float* qkv_b  = (const float*)d_in[2];
    const float* proj_w = (const float*)d_in[3];
    const float* proj_b = (const float*)d_in[4];
    const float* table  = (const float*)d_in[5];
    float* out = (float*)d_out;

    const int M  = 16 * 56 * 56;  // 50176 tokens
    const int Cd = 512, C3 = 1536;

    char* ws = (char*)d_ws;
    u16* QKV  = (u16*)ws;                                 // M*1536 bf16
    u16* Xb   = (u16*)(ws + (size_t)M * C3 * 2);          // M*512 bf16 (= Obuf)
    u16* Obuf = Xb;                                       // reused after gemm1
    u16* Wt1  = (u16*)(ws + (size_t)M * C3 * 2 + (size_t)M * Cd * 2);
    u16* Wt2  = Wt1 + (size_t)C3 * Cd;
    float* biasL = (float*)Wt1;  // 1 MB, aliases Wt1 (dead after gemm1)

    cvt_f32_bf16<<<(M * Cd) / 2048, 256, 0, stream>>>(x, Xb);

    dim3 tb(32, 32);
    transpose_cvt<<<dim3(C3 / 32, Cd / 32), tb, 0, stream>>>(qkv_w, Wt1, Cd, C3);
    transpose_cvt<<<dim3(Cd / 32, Cd / 32), tb, 0, stream>>>(proj_w, Wt2, Cd, Cd);

    // QKV = Xb @ qkv_w + qkv_b   (grid 392*6 = 2352, %8==0, 9.19 rounds)
    gemm128<false><<<dim3((M / 128) * (C3 / 256)), 512, 0, stream>>>(
        Xb, Wt1, qkv_b, nullptr, QKV, M, C3, Cd, C3 / 256);

    // bias+mask tables (into Wt1's space — Wt1 dead now)
    build_bias<<<dim3(64), 64, 0, stream>>>(table, biasL);

    // windowed attention (shift + partition + reverse fused)
    attn_kernel<<<dim3(1024 * 16), 64, 0, stream>>>(QKV, biasL, Obuf);

    // out = Obuf @ proj_w + proj_b + x   (grid 392*2 = 784, %8==0, 3.06 rounds)
    gemm128<true><<<dim3((M / 128) * (Cd / 256)), 512, 0, stream>>>(
        Obuf, Wt2, proj_b, x, out, M, Cd, Cd, Cd / 256);
}

// Round 3
// 455.362 us; speedup vs baseline: 1.0341x; 1.0341x over previous
//
#include <hip/hip_runtime.h>
#include <stdint.h>

typedef unsigned short u16;
typedef unsigned int   u32;

typedef __bf16 bf16x8 __attribute__((ext_vector_type(8)));
typedef float  f32x4  __attribute__((ext_vector_type(4)));

__device__ __forceinline__ float bf2f(u16 h) {
    return __uint_as_float(((u32)h) << 16);
}
__device__ __forceinline__ u16 f2bf(float f) {
    u32 u = __float_as_uint(f);
    u += 0x7FFFu + ((u >> 16) & 1u);   // RNE
    return (u16)(u >> 16);
}

#define GLOAD_LDS16(g, l)                                                     \
    __builtin_amdgcn_global_load_lds(                                         \
        (const __attribute__((address_space(1))) void*)(g),                   \
        (__attribute__((address_space(3))) void*)(l), 16, 0, 0)

// ---------------------------------------------------------------------------
// f32 -> bf16 bulk convert, 8 elems/thread
// ---------------------------------------------------------------------------
__global__ __launch_bounds__(256) void cvt_f32_bf16(const float* __restrict__ in,
                                                    u16* __restrict__ out) {
    int i = blockIdx.x * 256 + threadIdx.x;
    const float4* p = (const float4*)in + (size_t)i * 2;
    float4 a = p[0], b = p[1];
    union { u16 s[8]; uint4 v; } o;
    o.s[0] = f2bf(a.x); o.s[1] = f2bf(a.y); o.s[2] = f2bf(a.z); o.s[3] = f2bf(a.w);
    o.s[4] = f2bf(b.x); o.s[5] = f2bf(b.y); o.s[6] = f2bf(b.z); o.s[7] = f2bf(b.w);
    ((uint4*)out)[i] = o.v;
}

// ---------------------------------------------------------------------------
// Transpose+convert W[R][Cc] (f32) -> Wt[Cc][R] (bf16), dims multiple of 32
// ---------------------------------------------------------------------------
__global__ void transpose_cvt(const float* __restrict__ in, u16* __restrict__ out,
                              int R, int Cc) {
    __shared__ float tile[32][33];
    int c0 = blockIdx.x * 32, r0 = blockIdx.y * 32;
    int tx = threadIdx.x, ty = threadIdx.y;
    tile[ty][tx] = in[(size_t)(r0 + ty) * Cc + c0 + tx];
    __syncthreads();
    out[(size_t)(c0 + ty) * R + r0 + tx] = f2bf(tile[tx][ty]);
}

// ---------------------------------------------------------------------------
// Precompute bias+mask, swizzled to the MFMA C-fragment access pattern:
// biasL[cls][h][mi][ni][quad][l16][r] (float4 over r).
// ---------------------------------------------------------------------------
__global__ __launch_bounds__(64) void build_bias(const float* __restrict__ table,
                                                 float* __restrict__ biasL) {
    int cls = blockIdx.x >> 4;
    int h   = blockIdx.x & 15;
    int lane = threadIdx.x;
    int quad = lane >> 4, l16 = lane & 15;
    int eh = cls >> 1, ew = cls & 1;
    float* base = biasL + (size_t)(cls * 16 + h) * 4096;
#pragma unroll
    for (int mi = 0; mi < 4; mi++) {
#pragma unroll
        for (int ni = 0; ni < 4; ni++) {
            float4 v;
            float* vp = &v.x;
#pragma unroll
            for (int r = 0; r < 4; r++) {
                int m = mi * 16 + quad * 4 + r;
                int c = ni * 16 + l16;
                float b;
                if (c >= 49)      b = -1e9f;
                else if (m >= 49) b = 0.f;
                else {
                    int ty = m / 7, tx = m % 7, jy = c / 7, jx = c % 7;
                    b = table[((ty - jy + 6) * 13 + (tx - jx + 6)) * 16 + h];
                    int ridr = (eh ? (ty < 4 ? 1 : 2) : 0) * 3 + (ew ? (tx < 4 ? 1 : 2) : 0);
                    int ridc = (eh ? (jy < 4 ? 1 : 2) : 0) * 3 + (ew ? (jx < 4 ? 1 : 2) : 0);
                    if (ridr != ridc) b -= 100.f;
                }
                vp[r] = b;
            }
            ((float4*)base)[((mi * 4 + ni) * 4 + quad) * 16 + l16] = v;
        }
    }
}

// ---------------------------------------------------------------------------
// 256x256 4-phase GEMM (round-1 winner + epilogue lgkmcnt-only fix):
// C[M][N] = A[M][K] @ Bt[N][K]^T + bias[N] (+ res), A/Bt bf16, acc f32.
// 512 threads = 8 waves (2M x 4N), per-wave 128x64 output, BK=64.
// LDS 128 KiB double-buffered; XOR bank swizzle via inverse-permuted
// global_load_lds SOURCE + swizzled ds_read address. Counted vmcnt(4)
// once per K-tile (never 0 in steady state). setprio around MFMA
// clusters. XCD-aware blockIdx swizzle (grid % 8 == 0).
// ---------------------------------------------------------------------------
template <bool OUT_F32>
__global__ __launch_bounds__(512, 2) void gemm256(
    const u16* __restrict__ A, const u16* __restrict__ Bt,
    const float* __restrict__ bias, const float* __restrict__ res,
    void* __restrict__ Cout, int M, int N, int K, int GX)
{
    __shared__ __align__(16) char smem[131072];
    char* AsB = smem;            // A: 2 bufs x (2 halves x 128 x 64 bf16) = 64 KiB
    char* BsB = smem + 65536;    // B: same

    // ---- XCD-aware swizzle (bijective: gridDim.x % 8 == 0) ----
    const int nwg = (int)gridDim.x;
    int wg = (int)blockIdx.x;
    wg = (wg & 7) * (nwg >> 3) + (wg >> 3);
    const int bx = wg % GX;
    const int by = wg / GX;
    const size_t m0 = (size_t)by * 256;
    const size_t n0 = (size_t)bx * 256;

    const int t    = threadIdx.x;
    const int lane = t & 63;
    const int w    = t >> 6;
    const int wm   = w >> 2, wn = w & 3;
    const int quad = lane >> 4, l16 = lane & 15;
    const int xr   = l16 & 7;
    const int cb   = (quad ^ xr) * 16;       // swizzled 16B chunk base (ks=0)

    // ---- staging geometry: thread t covers rows r0 (j=0) and r0+64 (j=1) ----
    const int r0  = t >> 3;                  // 0..63
    const int s8  = t & 7;                   // 16B slot within 128B row
    const int swz = (s8 ^ (r0 & 7)) * 8;     // inverse-permuted source chunk
    const u16* Ag0 = A  + (m0 + r0) * K + swz;
    const u16* Bg0 = Bt + (n0 + r0) * K + swz;
    const size_t j64K = (size_t)64 * K;
    const int lo0 = t * 16, lo1 = t * 16 + 8192;

    auto stageA = [&](int bf, int half, int ktt) {
        char* d = AsB + bf * 32768 + half * 16384;
        const u16* g = Ag0 + (size_t)half * 128 * K + ktt * 64;
        GLOAD_LDS16(g, d + lo0);
        GLOAD_LDS16(g + j64K, d + lo1);
    };
    auto stageB = [&](int bf, int half, int ktt) {
        char* d = BsB + bf * 32768 + half * 16384;
        const u16* g = Bg0 + (size_t)half * 128 * K + ktt * 64;
        GLOAD_LDS16(g, d + lo0);
        GLOAD_LDS16(g + j64K, d + lo1);
    };

    f32x4 acc[8][4];
    const f32x4 fz = {0.f, 0.f, 0.f, 0.f};
#pragma unroll
    for (int i = 0; i < 8; i++)
#pragma unroll
        for (int j = 0; j < 4; j++) acc[i][j] = fz;

    const int NT = K >> 6;

    // ---- prologue: K-tile 0 complete + first 2 half-tiles of K-tile 1 ----
    stageA(0, 0, 0); stageA(0, 1, 0); stageB(0, 0, 0); stageB(0, 1, 0);
    stageB(1, 0, 1); stageA(1, 0, 1);
    asm volatile("s_waitcnt vmcnt(4)" ::: "memory");   // K-tile 0 landed
    __builtin_amdgcn_s_barrier();

    for (int kt = 0; kt < NT; ++kt) {
        const int buf = kt & 1;
        const char* Ab  = AsB + buf * 32768 + wm * 16384 + l16 * 128;
        const char* Bb  = BsB + buf * 32768 + (wn >> 1) * 16384 + (wn & 1) * 8192 + l16 * 128;
        const char* pA0 = Ab + cb;
        const char* pA1 = Ab + (cb ^ 64);
        const char* pB0 = Bb + cb;
        const char* pB1 = Bb + (cb ^ 64);

        bf16x8 a[4][2], b0[2][2], b1[2][2];

        // ================= phase 1: Q(0,0) =================
#pragma unroll
        for (int mi = 0; mi < 4; mi++) {
            a[mi][0] = *(const bf16x8*)(pA0 + mi * 2048);
            a[mi][1] = *(const bf16x8*)(pA1 + mi * 2048);
        }
#pragma unroll
        for (int nj = 0; nj < 2; nj++) {
            b0[nj][0] = *(const bf16x8*)(pB0 + nj * 2048);
            b0[nj][1] = *(const bf16x8*)(pB1 + nj * 2048);
        }
        if (kt + 1 < NT) stageA((kt + 1) & 1, 1, kt + 1);
        __builtin_amdgcn_s_barrier();
        asm volatile("s_waitcnt lgkmcnt(0)" ::: "memory");
        __builtin_amdgcn_s_setprio(1);
#pragma unroll
        for (int mi = 0; mi < 4; mi++)
#pragma unroll
            for (int nj = 0; nj < 2; nj++) {
                acc[mi][nj] = __builtin_amdgcn_mfma_f32_16x16x32_bf16(
                    a[mi][0], b0[nj][0], acc[mi][nj], 0, 0, 0);
                acc[mi][nj] = __builtin_amdgcn_mfma_f32_16x16x32_bf16(
                    a[mi][1], b0[nj][1], acc[mi][nj], 0, 0, 0);
            }
        __builtin_amdgcn_s_setprio(0);
        __builtin_amdgcn_s_barrier();

        // ================= phase 2: Q(0,1) =================
#pragma unroll
        for (int nj = 0; nj < 2; nj++) {
            b1[nj][0] = *(const bf16x8*)(pB0 + 4096 + nj * 2048);
            b1[nj][1] = *(const bf16x8*)(pB1 + 4096 + nj * 2048);
        }
        if (kt + 1 < NT) stageB((kt + 1) & 1, 1, kt + 1);
        __builtin_amdgcn_s_barrier();
        asm volatile("s_waitcnt lgkmcnt(0)" ::: "memory");
        __builtin_amdgcn_s_setprio(1);
#pragma unroll
        for (int mi = 0; mi < 4; mi++)
#pragma unroll
            for (int nj = 0; nj < 2; nj++) {
                acc[mi][2 + nj] = __builtin_amdgcn_mfma_f32_16x16x32_bf16(
                    a[mi][0], b1[nj][0], acc[mi][2 + nj], 0, 0, 0);
                acc[mi][2 + nj] = __builtin_amdgcn_mfma_f32_16x16x32_bf16(
                    a[mi][1], b1[nj][1], acc[mi][2 + nj], 0, 0, 0);
            }
        __builtin_amdgcn_s_setprio(0);
        __builtin_amdgcn_s_barrier();

        // ================= phase 3: Q(1,1) =================
#pragma unroll
        for (int mi = 0; mi < 4; mi++) {
            a[mi][0] = *(const bf16x8*)(pA0 + 8192 + mi * 2048);
            a[mi][1] = *(const bf16x8*)(pA1 + 8192 + mi * 2048);
        }
        if (kt + 2 < NT) stageB(buf, 0, kt + 2);   // B-reads of this buf done (ph2 barrier)
        __builtin_amdgcn_s_barrier();
        asm volatile("s_waitcnt lgkmcnt(0)" ::: "memory");
        __builtin_amdgcn_s_setprio(1);
#pragma unroll
        for (int mi = 0; mi < 4; mi++)
#pragma unroll
            for (int nj = 0; nj < 2; nj++) {
                acc[4 + mi][2 + nj] = __builtin_amdgcn_mfma_f32_16x16x32_bf16(
                    a[mi][0], b1[nj][0], acc[4 + mi][2 + nj], 0, 0, 0);
                acc[4 + mi][2 + nj] = __builtin_amdgcn_mfma_f32_16x16x32_bf16(
                    a[mi][1], b1[nj][1], acc[4 + mi][2 + nj], 0, 0, 0);
            }
        __builtin_amdgcn_s_setprio(0);
        __builtin_amdgcn_s_barrier();

        // ================= phase 4: Q(1,0) =================
        if (kt + 2 < NT) stageA(buf, 0, kt + 2);   // A-reads of this buf done (ph3 barrier)
        __builtin_amdgcn_s_barrier();
        __builtin_amdgcn_s_setprio(1);
#pragma unroll
        for (int mi = 0; mi < 4; mi++)
#pragma unroll
            for (int nj = 0; nj < 2; nj++) {
                acc[4 + mi][nj] = __builtin_amdgcn_mfma_f32_16x16x32_bf16(
                    a[mi][0], b0[nj][0], acc[4 + mi][nj], 0, 0, 0);
                acc[4 + mi][nj] = __builtin_amdgcn_mfma_f32_16x16x32_bf16(
                    a[mi][1], b0[nj][1], acc[4 + mi][nj], 0, 0, 0);
            }
        __builtin_amdgcn_s_setprio(0);
        // counted wait: next K-tile fully landed, 2 half-tiles stay in flight
        if (kt < NT - 2) asm volatile("s_waitcnt vmcnt(4)" ::: "memory");
        else             asm volatile("s_waitcnt vmcnt(0)" ::: "memory");
        __builtin_amdgcn_s_barrier();
    }

    // ---- epilogue: per-wave LDS transpose -> vectorized stores ----
    // lgkmcnt-only waits: ds ordering is per-wave; do NOT drain global
    // stores each mi-step (the old s_waitcnt(0) cost ~500-900 cyc x 8).
    float* scr = (float*)(void*)smem + w * 1088;   // [16][68] f32 per wave
    float bv[4];
#pragma unroll
    for (int nj = 0; nj < 4; nj++)
        bv[nj] = bias[n0 + wn * 64 + nj * 16 + l16];

    const size_t colb = n0 + wn * 64 + quad * 16;
#pragma unroll
    for (int mi = 0; mi < 8; mi++) {
#pragma unroll
        for (int nj = 0; nj < 4; nj++)
#pragma unroll
            for (int r = 0; r < 4; r++)
                scr[(quad * 4 + r) * 68 + nj * 16 + l16] = acc[mi][nj][r] + bv[nj];
        asm volatile("s_waitcnt lgkmcnt(0)" ::: "memory");  // ds writes visible

        const size_t row = m0 + wm * 128 + mi * 16 + l16;
        const float4* sp = (const float4*)(scr + l16 * 68 + quad * 16);
        float4 v0 = sp[0], v1 = sp[1], v2 = sp[2], v3 = sp[3];

        if (OUT_F32) {
            const float4* rp = (const float4*)(res + row * N + colb);
            float4 r0v = rp[0], r1v = rp[1], r2v = rp[2], r3v = rp[3];
            v0.x += r0v.x; v0.y += r0v.y; v0.z += r0v.z; v0.w += r0v.w;
            v1.x += r1v.x; v1.y += r1v.y; v1.z += r1v.z; v1.w += r1v.w;
            v2.x += r2v.x; v2.y += r2v.y; v2.z += r2v.z; v2.w += r2v.w;
            v3.x += r3v.x; v3.y += r3v.y; v3.z += r3v.z; v3.w += r3v.w;
            float4* op = (float4*)((float*)Cout + row * N + colb);
            op[0] = v0; op[1] = v1; op[2] = v2; op[3] = v3;
        } else {
            union { u16 s[8]; uint4 q; } p0, p1;
            p0.s[0] = f2bf(v0.x); p0.s[1] = f2bf(v0.y); p0.s[2] = f2bf(v0.z); p0.s[3] = f2bf(v0.w);
            p0.s[4] = f2bf(v1.x); p0.s[5] = f2bf(v1.y); p0.s[6] = f2bf(v1.z); p0.s[7] = f2bf(v1.w);
            p1.s[0] = f2bf(v2.x); p1.s[1] = f2bf(v2.y); p1.s[2] = f2bf(v2.z); p1.s[3] = f2bf(v2.w);
            p1.s[4] = f2bf(v3.x); p1.s[5] = f2bf(v3.y); p1.s[6] = f2bf(v3.z); p1.s[7] = f2bf(v3.w);
            uint4* op = (uint4*)((u16*)Cout + row * N + colb);
            op[0] = p0.q; op[1] = p1.q;
        }
        asm volatile("s_waitcnt lgkmcnt(0)" ::: "memory");  // scratch reads done
    }
}

// ---------------------------------------------------------------------------
// Attention v3: 1 wave per (window, head). Unchanged (isolation round).
// ---------------------------------------------------------------------------
__global__ __launch_bounds__(64) void attn_kernel(
    const u16* __restrict__ qkv, const float* __restrict__ biasL,
    u16* __restrict__ O)
{
    __shared__ __align__(16) u16 Ps[64 * 72];   // 9216 B
    __shared__ __align__(16) u16 Vts[32 * 72];  // 4608 B

    const int wid = blockIdx.x >> 4;
    const int h   = blockIdx.x & 15;
    const int b   = wid >> 6;
    const int wy  = (wid >> 3) & 7;
    const int wx  = wid & 7;
    const int cls = ((wy == 7) ? 2 : 0) + ((wx == 7) ? 1 : 0);
    const int lane = threadIdx.x;
    const int quad = lane >> 4, l16 = lane & 15;

    auto tokOf = [&](int m) -> size_t {
        int tt = m < 49 ? m : 48;
        int ty = tt / 7, tx = tt - ty * 7;
        int ho = wy * 7 + ty + 3; if (ho >= 56) ho -= 56;
        int wo = wx * 7 + tx + 3; if (wo >= 56) wo -= 56;
        return ((size_t)b * 56 + ho) * 56 + wo;
    };

    {
        size_t tok = tokOf(lane);
        const uint4* vs = (const uint4*)(qkv + tok * 1536 + 1024 + h * 32);
        union { uint4 u4[4]; u16 s[32]; } vb;
        vb.u4[0] = vs[0]; vb.u4[1] = vs[1]; vb.u4[2] = vs[2]; vb.u4[3] = vs[3];
#pragma unroll
        for (int d = 0; d < 32; d++) Vts[d * 72 + lane] = vb.s[d];
    }

    bf16x8 aq[4], bk[4];
#pragma unroll
    for (int i = 0; i < 4; i++) {
        size_t tok = tokOf(i * 16 + l16);
        const u16* base = qkv + tok * 1536 + h * 32 + quad * 8;
        aq[i] = *(const bf16x8*)base;
        bk[i] = *(const bf16x8*)(base + 512);
    }

    f32x4 acc[4][4];
    {
        const f32x4 fzz = {0.f, 0.f, 0.f, 0.f};
#pragma unroll
        for (int mi = 0; mi < 4; mi++)
#pragma unroll
            for (int ni = 0; ni < 4; ni++)
                acc[mi][ni] = __builtin_amdgcn_mfma_f32_16x16x32_bf16(
                    aq[mi], bk[ni], fzz, 0, 0, 0);
    }

    {
        const float scale = 0.17677669529663687f;  // 1/sqrt(32)
        const float* bp = biasL + (size_t)(cls * 16 + h) * 4096;
#pragma unroll
        for (int mi = 0; mi < 4; mi++)
#pragma unroll
            for (int ni = 0; ni < 4; ni++) {
                float4 bvv = ((const float4*)bp)[((mi * 4 + ni) * 4 + quad) * 16 + l16];
                const float* bvp = &bvv.x;
#pragma unroll
                for (int r = 0; r < 4; r++)
                    acc[mi][ni][r] = acc[mi][ni][r] * scale + bvp[r];
            }
    }

    float rinv[4][4];
    {
#pragma unroll
        for (int mi = 0; mi < 4; mi++)
#pragma unroll
            for (int r = 0; r < 4; r++) {
                float m0 = fmaxf(fmaxf(acc[mi][0][r], acc[mi][1][r]),
                                 fmaxf(acc[mi][2][r], acc[mi][3][r]));
                m0 = fmaxf(m0, __shfl_xor(m0, 1, 64));
                m0 = fmaxf(m0, __shfl_xor(m0, 2, 64));
                m0 = fmaxf(m0, __shfl_xor(m0, 4, 64));
                m0 = fmaxf(m0, __shfl_xor(m0, 8, 64));
                float e0 = __expf(acc[mi][0][r] - m0);
                float e1 = __expf(acc[mi][1][r] - m0);
                float e2 = __expf(acc[mi][2][r] - m0);
                float e3 = __expf(acc[mi][3][r] - m0);
                acc[mi][0][r] = e0; acc[mi][1][r] = e1;
                acc[mi][2][r] = e2; acc[mi][3][r] = e3;
                float s0 = (e0 + e1) + (e2 + e3);
                s0 += __shfl_xor(s0, 1, 64);
                s0 += __shfl_xor(s0, 2, 64);
                s0 += __shfl_xor(s0, 4, 64);
                s0 += __shfl_xor(s0, 8, 64);
                rinv[mi][r] = __builtin_amdgcn_rcpf(s0);
            }
    }

#pragma unroll
    for (int mi = 0; mi < 4; mi++)
#pragma unroll
        for (int ni = 0; ni < 4; ni++)
#pragma unroll
            for (int r = 0; r < 4; r++)
                Ps[(mi * 16 + quad * 4 + r) * 72 + ni * 16 + l16] =
                    f2bf(acc[mi][ni][r]);
    __syncthreads();

#pragma unroll
    for (int mi = 0; mi < 4; mi++) {
        f32x4 c0 = {0.f, 0.f, 0.f, 0.f}, c1 = {0.f, 0.f, 0.f, 0.f};
#pragma unroll
        for (int ks = 0; ks < 2; ks++) {
            bf16x8 a = *(const bf16x8*)(Ps + (mi * 16 + l16) * 72 + ks * 32 + quad * 8);
            bf16x8 b0 = *(const bf16x8*)(Vts + l16 * 72 + ks * 32 + quad * 8);
            bf16x8 b1 = *(const bf16x8*)(Vts + (16 + l16) * 72 + ks * 32 + quad * 8);
            c0 = __builtin_amdgcn_mfma_f32_16x16x32_bf16(a, b0, c0, 0, 0, 0);
            c1 = __builtin_amdgcn_mfma_f32_16x16x32_bf16(a, b1, c1, 0, 0, 0);
        }
#pragma unroll
        for (int r = 0; r < 4; r++) {
            int m = mi * 16 + quad * 4 + r;
            if (m < 49) {
                int ty = m / 7, tx = m - ty * 7;
                int ho = wy * 7 + ty + 3; if (ho >= 56) ho -= 56;
                int wo = wx * 7 + tx + 3; if (wo >= 56) wo -= 56;
                size_t tok = ((size_t)b * 56 + ho) * 56 + wo;
                u16* op = O + tok * 512 + h * 32 + l16;
                op[0]  = f2bf(c0[r] * rinv[mi][r]);
                op[16] = f2bf(c1[r] * rinv[mi][r]);
            }
        }
    }
}

// ---------------------------------------------------------------------------
extern "C" void kernel_launch(void* const* d_in, const int* in_sizes, int n_in,
                              void* d_out, int out_size, void* d_ws, size_t ws_size,
                              hipStream_t stream)
{
    const float* x      = (const float*)d_in[0];
    const float* qkv_w  = (const float*)d_in[1];
    const float* qkv_b  = (const float*)d_in[2];
    const float* proj_w = (const float*)d_in[3];
    const float* proj_b = (const float*)d_in[4];
    const float* table  = (const float*)d_in[5];
    float* out = (float*)d_out;

    const int M  = 16 * 56 * 56;  // 50176 tokens
    const int Cd = 512, C3 = 1536;

    char* ws = (char*)d_ws;
    u16* QKV  = (u16*)ws;                                 // M*1536 bf16
    u16* Xb   = (u16*)(ws + (size_t)M * C3 * 2);          // M*512 bf16 (= Obuf)
    u16* Obuf = Xb;                                       // reused after gemm1
    u16* Wt1  = (u16*)(ws + (size_t)M * C3 * 2 + (size_t)M * Cd * 2);
    u16* Wt2  = Wt1 + (size_t)C3 * Cd;
    float* biasL = (float*)Wt1;  // 1 MB, aliases Wt1 (dead after gemm1)

    cvt_f32_bf16<<<(M * Cd) / 2048, 256, 0, stream>>>(x, Xb);

    dim3 tb(32, 32);
    transpose_cvt<<<dim3(C3 / 32, Cd / 32), tb, 0, stream>>>(qkv_w, Wt1, Cd, C3);
    transpose_cvt<<<dim3(Cd / 32, Cd / 32), tb, 0, stream>>>(proj_w, Wt2, Cd, Cd);

    // QKV = Xb @ qkv_w + qkv_b   (grid 196*6 = 1176, %8==0)
    gemm256<false><<<dim3((M / 256) * (C3 / 256)), 512, 0, stream>>>(
        Xb, Wt1, qkv_b, nullptr, QKV, M, C3, Cd, C3 / 256);

    // bias+mask tables (into Wt1's space — Wt1 dead now)
    build_bias<<<dim3(64), 64, 0, stream>>>(table, biasL);

    // windowed attention (shift + partition + reverse fused)
    attn_kernel<<<dim3(1024 * 16), 64, 0, stream>>>(QKV, biasL, Obuf);

    // out = Obuf @ proj_w + proj_b + x   (grid 196*2 = 392, %8==0)
    gemm256<true><<<dim3((M / 256) * (Cd / 256)), 512, 0, stream>>>(
        Obuf, Wt2, proj_b, x, out, M, Cd, Cd, Cd / 256);
}

// Round 5
// 452.614 us; speedup vs baseline: 1.0404x; 1.0061x over previous
//
#include <hip/hip_runtime.h>
#include <stdint.h>

typedef unsigned short u16;
typedef unsigned int   u32;

typedef __bf16 bf16x8 __attribute__((ext_vector_type(8)));
typedef float  f32x4  __attribute__((ext_vector_type(4)));

__device__ __forceinline__ float bf2f(u16 h) {
    return __uint_as_float(((u32)h) << 16);
}
__device__ __forceinline__ u16 f2bf(float f) {
    u32 u = __float_as_uint(f);
    u += 0x7FFFu + ((u >> 16) & 1u);   // RNE
    return (u16)(u >> 16);
}

#define GLOAD_LDS16(g, l)                                                     \
    __builtin_amdgcn_global_load_lds(                                         \
        (const __attribute__((address_space(1))) void*)(g),                   \
        (__attribute__((address_space(3))) void*)(l), 16, 0, 0)

// ---------------------------------------------------------------------------
// Merged prep: f32->bf16 cvt of x (3136 blocks) + transpose_cvt of qkv_w
// (768 blocks) + transpose_cvt of proj_w (256 blocks). One launch, 1024 thr.
// ---------------------------------------------------------------------------
__global__ __launch_bounds__(1024) void prep_kernel(
    const float* __restrict__ x,      u16* __restrict__ Xb,
    const float* __restrict__ qkv_w,  u16* __restrict__ Wt1,
    const float* __restrict__ proj_w, u16* __restrict__ Wt2)
{
    __shared__ float tile[32][33];
    const int bid = blockIdx.x;
    const int t   = threadIdx.x;

    if (bid < 3136) {                          // ---- cvt x -> Xb (8 f32/thr)
        int i = bid * 1024 + t;
        const float4* p = (const float4*)x + (size_t)i * 2;
        float4 a = p[0], b = p[1];
        union { u16 s[8]; uint4 v; } o;
        o.s[0] = f2bf(a.x); o.s[1] = f2bf(a.y); o.s[2] = f2bf(a.z); o.s[3] = f2bf(a.w);
        o.s[4] = f2bf(b.x); o.s[5] = f2bf(b.y); o.s[6] = f2bf(b.z); o.s[7] = f2bf(b.w);
        ((uint4*)Xb)[i] = o.v;
    } else if (bid < 3136 + 768) {             // ---- qkv_w [512][1536] -> Wt1
        int lb = bid - 3136;
        int c0 = (lb % 48) * 32, r0 = (lb / 48) * 32;
        int tx = t & 31, ty = t >> 5;
        tile[ty][tx] = qkv_w[(size_t)(r0 + ty) * 1536 + c0 + tx];
        __syncthreads();
        Wt1[(size_t)(c0 + ty) * 512 + r0 + tx] = f2bf(tile[tx][ty]);
    } else {                                   // ---- proj_w [512][512] -> Wt2
        int lb = bid - 3904;
        int c0 = (lb & 15) * 32, r0 = (lb >> 4) * 32;
        int tx = t & 31, ty = t >> 5;
        tile[ty][tx] = proj_w[(size_t)(r0 + ty) * 512 + c0 + tx];
        __syncthreads();
        Wt2[(size_t)(c0 + ty) * 512 + r0 + tx] = f2bf(tile[tx][ty]);
    }
}

// ---------------------------------------------------------------------------
// Precompute bias+mask in the TRANSPOSED (S^T) MFMA C-fragment pattern:
// biasT[cls][h][ki][nj][quad][l16][r]; component r maps to
// k = ki*16+quad*4+r (key token, C row), m = nj*16+l16 (query token, C col).
// Keys k>=49 get -1e9 (pad vanishes in softmax); rows m>=49 are never stored.
// ---------------------------------------------------------------------------
__global__ __launch_bounds__(64) void build_bias(const float* __restrict__ table,
                                                 float* __restrict__ biasT) {
    int cls = blockIdx.x >> 4;
    int h   = blockIdx.x & 15;
    int lane = threadIdx.x;
    int quad = lane >> 4, l16 = lane & 15;
    int eh = cls >> 1, ew = cls & 1;
    float* base = biasT + (size_t)(cls * 16 + h) * 4096;
#pragma unroll
    for (int ki = 0; ki < 4; ki++) {
#pragma unroll
        for (int nj = 0; nj < 4; nj++) {
            float4 v;
            float* vp = &v.x;
#pragma unroll
            for (int r = 0; r < 4; r++) {
                int k = ki * 16 + quad * 4 + r;   // key token
                int m = nj * 16 + l16;            // query token
                float b;
                if (k >= 49)      b = -1e9f;
                else if (m >= 49) b = 0.f;
                else {
                    int ty = m / 7, tx = m % 7, jy = k / 7, jx = k % 7;
                    b = table[((ty - jy + 6) * 13 + (tx - jx + 6)) * 16 + h];
                    int ridr = (eh ? (ty < 4 ? 1 : 2) : 0) * 3 + (ew ? (tx < 4 ? 1 : 2) : 0);
                    int ridc = (eh ? (jy < 4 ? 1 : 2) : 0) * 3 + (ew ? (jx < 4 ? 1 : 2) : 0);
                    if (ridr != ridc) b -= 100.f;
                }
                vp[r] = b;
            }
            ((float4*)base)[((ki * 4 + nj) * 4 + quad) * 16 + l16] = v;
        }
    }
}

// ---------------------------------------------------------------------------
// 256x256 4-phase GEMM (round-3 variant, unchanged — best measured).
// ---------------------------------------------------------------------------
template <bool OUT_F32>
__global__ __launch_bounds__(512, 2) void gemm256(
    const u16* __restrict__ A, const u16* __restrict__ Bt,
    const float* __restrict__ bias, const float* __restrict__ res,
    void* __restrict__ Cout, int M, int N, int K, int GX)
{
    __shared__ __align__(16) char smem[131072];
    char* AsB = smem;            // A: 2 bufs x (2 halves x 128 x 64 bf16) = 64 KiB
    char* BsB = smem + 65536;    // B: same

    // ---- XCD-aware swizzle (bijective: gridDim.x % 8 == 0) ----
    const int nwg = (int)gridDim.x;
    int wg = (int)blockIdx.x;
    wg = (wg & 7) * (nwg >> 3) + (wg >> 3);
    const int bx = wg % GX;
    const int by = wg / GX;
    const size_t m0 = (size_t)by * 256;
    const size_t n0 = (size_t)bx * 256;

    const int t    = threadIdx.x;
    const int lane = t & 63;
    const int w    = t >> 6;
    const int wm   = w >> 2, wn = w & 3;
    const int quad = lane >> 4, l16 = lane & 15;
    const int xr   = l16 & 7;
    const int cb   = (quad ^ xr) * 16;       // swizzled 16B chunk base (ks=0)

    // ---- staging geometry: thread t covers rows r0 (j=0) and r0+64 (j=1) ----
    const int r0  = t >> 3;                  // 0..63
    const int s8  = t & 7;                   // 16B slot within 128B row
    const int swz = (s8 ^ (r0 & 7)) * 8;     // inverse-permuted source chunk
    const u16* Ag0 = A  + (m0 + r0) * K + swz;
    const u16* Bg0 = Bt + (n0 + r0) * K + swz;
    const size_t j64K = (size_t)64 * K;
    const int lo0 = t * 16, lo1 = t * 16 + 8192;

    auto stageA = [&](int bf, int half, int ktt) {
        char* d = AsB + bf * 32768 + half * 16384;
        const u16* g = Ag0 + (size_t)half * 128 * K + ktt * 64;
        GLOAD_LDS16(g, d + lo0);
        GLOAD_LDS16(g + j64K, d + lo1);
    };
    auto stageB = [&](int bf, int half, int ktt) {
        char* d = BsB + bf * 32768 + half * 16384;
        const u16* g = Bg0 + (size_t)half * 128 * K + ktt * 64;
        GLOAD_LDS16(g, d + lo0);
        GLOAD_LDS16(g + j64K, d + lo1);
    };

    f32x4 acc[8][4];
    const f32x4 fz = {0.f, 0.f, 0.f, 0.f};
#pragma unroll
    for (int i = 0; i < 8; i++)
#pragma unroll
        for (int j = 0; j < 4; j++) acc[i][j] = fz;

    const int NT = K >> 6;

    // ---- prologue: K-tile 0 complete + first 2 half-tiles of K-tile 1 ----
    stageA(0, 0, 0); stageA(0, 1, 0); stageB(0, 0, 0); stageB(0, 1, 0);
    stageB(1, 0, 1); stageA(1, 0, 1);
    asm volatile("s_waitcnt vmcnt(4)" ::: "memory");   // K-tile 0 landed
    __builtin_amdgcn_s_barrier();

    for (int kt = 0; kt < NT; ++kt) {
        const int buf = kt & 1;
        const char* Ab  = AsB + buf * 32768 + wm * 16384 + l16 * 128;
        const char* Bb  = BsB + buf * 32768 + (wn >> 1) * 16384 + (wn & 1) * 8192 + l16 * 128;
        const char* pA0 = Ab + cb;
        const char* pA1 = Ab + (cb ^ 64);
        const char* pB0 = Bb + cb;
        const char* pB1 = Bb + (cb ^ 64);

        bf16x8 a[4][2], b0[2][2], b1[2][2];

        // ================= phase 1: Q(0,0) =================
#pragma unroll
        for (int mi = 0; mi < 4; mi++) {
            a[mi][0] = *(const bf16x8*)(pA0 + mi * 2048);
            a[mi][1] = *(const bf16x8*)(pA1 + mi * 2048);
        }
#pragma unroll
        for (int nj = 0; nj < 2; nj++) {
            b0[nj][0] = *(const bf16x8*)(pB0 + nj * 2048);
            b0[nj][1] = *(const bf16x8*)(pB1 + nj * 2048);
        }
        if (kt + 1 < NT) stageA((kt + 1) & 1, 1, kt + 1);
        __builtin_amdgcn_s_barrier();
        asm volatile("s_waitcnt lgkmcnt(0)" ::: "memory");
        __builtin_amdgcn_s_setprio(1);
#pragma unroll
        for (int mi = 0; mi < 4; mi++)
#pragma unroll
            for (int nj = 0; nj < 2; nj++) {
                acc[mi][nj] = __builtin_amdgcn_mfma_f32_16x16x32_bf16(
                    a[mi][0], b0[nj][0], acc[mi][nj], 0, 0, 0);
                acc[mi][nj] = __builtin_amdgcn_mfma_f32_16x16x32_bf16(
                    a[mi][1], b0[nj][1], acc[mi][nj], 0, 0, 0);
            }
        __builtin_amdgcn_s_setprio(0);
        __builtin_amdgcn_s_barrier();

        // ================= phase 2: Q(0,1) =================
#pragma unroll
        for (int nj = 0; nj < 2; nj++) {
            b1[nj][0] = *(const bf16x8*)(pB0 + 4096 + nj * 2048);
            b1[nj][1] = *(const bf16x8*)(pB1 + 4096 + nj * 2048);
        }
        if (kt + 1 < NT) stageB((kt + 1) & 1, 1, kt + 1);
        __builtin_amdgcn_s_barrier();
        asm volatile("s_waitcnt lgkmcnt(0)" ::: "memory");
        __builtin_amdgcn_s_setprio(1);
#pragma unroll
        for (int mi = 0; mi < 4; mi++)
#pragma unroll
            for (int nj = 0; nj < 2; nj++) {
                acc[mi][2 + nj] = __builtin_amdgcn_mfma_f32_16x16x32_bf16(
                    a[mi][0], b1[nj][0], acc[mi][2 + nj], 0, 0, 0);
                acc[mi][2 + nj] = __builtin_amdgcn_mfma_f32_16x16x32_bf16(
                    a[mi][1], b1[nj][1], acc[mi][2 + nj], 0, 0, 0);
            }
        __builtin_amdgcn_s_setprio(0);
        __builtin_amdgcn_s_barrier();

        // ================= phase 3: Q(1,1) =================
#pragma unroll
        for (int mi = 0; mi < 4; mi++) {
            a[mi][0] = *(const bf16x8*)(pA0 + 8192 + mi * 2048);
            a[mi][1] = *(const bf16x8*)(pA1 + 8192 + mi * 2048);
        }
        if (kt + 2 < NT) stageB(buf, 0, kt + 2);   // B-reads of this buf done (ph2 barrier)
        __builtin_amdgcn_s_barrier();
        asm volatile("s_waitcnt lgkmcnt(0)" ::: "memory");
        __builtin_amdgcn_s_setprio(1);
#pragma unroll
        for (int mi = 0; mi < 4; mi++)
#pragma unroll
            for (int nj = 0; nj < 2; nj++) {
                acc[4 + mi][2 + nj] = __builtin_amdgcn_mfma_f32_16x16x32_bf16(
                    a[mi][0], b1[nj][0], acc[4 + mi][2 + nj], 0, 0, 0);
                acc[4 + mi][2 + nj] = __builtin_amdgcn_mfma_f32_16x16x32_bf16(
                    a[mi][1], b1[nj][1], acc[4 + mi][2 + nj], 0, 0, 0);
            }
        __builtin_amdgcn_s_setprio(0);
        __builtin_amdgcn_s_barrier();

        // ================= phase 4: Q(1,0) =================
        if (kt + 2 < NT) stageA(buf, 0, kt + 2);   // A-reads of this buf done (ph3 barrier)
        __builtin_amdgcn_s_barrier();
        __builtin_amdgcn_s_setprio(1);
#pragma unroll
        for (int mi = 0; mi < 4; mi++)
#pragma unroll
            for (int nj = 0; nj < 2; nj++) {
                acc[4 + mi][nj] = __builtin_amdgcn_mfma_f32_16x16x32_bf16(
                    a[mi][0], b0[nj][0], acc[4 + mi][nj], 0, 0, 0);
                acc[4 + mi][nj] = __builtin_amdgcn_mfma_f32_16x16x32_bf16(
                    a[mi][1], b0[nj][1], acc[4 + mi][nj], 0, 0, 0);
            }
        __builtin_amdgcn_s_setprio(0);
        // counted wait: next K-tile fully landed, 2 half-tiles stay in flight
        if (kt < NT - 2) asm volatile("s_waitcnt vmcnt(4)" ::: "memory");
        else             asm volatile("s_waitcnt vmcnt(0)" ::: "memory");
        __builtin_amdgcn_s_barrier();
    }

    // ---- epilogue: per-wave LDS transpose -> vectorized stores ----
    float* scr = (float*)(void*)smem + w * 1088;   // [16][68] f32 per wave
    float bv[4];
#pragma unroll
    for (int nj = 0; nj < 4; nj++)
        bv[nj] = bias[n0 + wn * 64 + nj * 16 + l16];

    const size_t colb = n0 + wn * 64 + quad * 16;
#pragma unroll
    for (int mi = 0; mi < 8; mi++) {
#pragma unroll
        for (int nj = 0; nj < 4; nj++)
#pragma unroll
            for (int r = 0; r < 4; r++)
                scr[(quad * 4 + r) * 68 + nj * 16 + l16] = acc[mi][nj][r] + bv[nj];
        asm volatile("s_waitcnt lgkmcnt(0)" ::: "memory");  // ds writes visible

        const size_t row = m0 + wm * 128 + mi * 16 + l16;
        const float4* sp = (const float4*)(scr + l16 * 68 + quad * 16);
        float4 v0 = sp[0], v1 = sp[1], v2 = sp[2], v3 = sp[3];

        if (OUT_F32) {
            const float4* rp = (const float4*)(res + row * N + colb);
            float4 r0v = rp[0], r1v = rp[1], r2v = rp[2], r3v = rp[3];
            v0.x += r0v.x; v0.y += r0v.y; v0.z += r0v.z; v0.w += r0v.w;
            v1.x += r1v.x; v1.y += r1v.y; v1.z += r1v.z; v1.w += r1v.w;
            v2.x += r2v.x; v2.y += r2v.y; v2.z += r2v.z; v2.w += r2v.w;
            v3.x += r3v.x; v3.y += r3v.y; v3.z += r3v.z; v3.w += r3v.w;
            float4* op = (float4*)((float*)Cout + row * N + colb);
            op[0] = v0; op[1] = v1; op[2] = v2; op[3] = v3;
        } else {
            union { u16 s[8]; uint4 q; } p0, p1;
            p0.s[0] = f2bf(v0.x); p0.s[1] = f2bf(v0.y); p0.s[2] = f2bf(v0.z); p0.s[3] = f2bf(v0.w);
            p0.s[4] = f2bf(v1.x); p0.s[5] = f2bf(v1.y); p0.s[6] = f2bf(v1.z); p0.s[7] = f2bf(v1.w);
            p1.s[0] = f2bf(v2.x); p1.s[1] = f2bf(v2.y); p1.s[2] = f2bf(v2.z); p1.s[3] = f2bf(v2.w);
            p1.s[4] = f2bf(v3.x); p1.s[5] = f2bf(v3.y); p1.s[6] = f2bf(v3.z); p1.s[7] = f2bf(v3.w);
            uint4* op = (uint4*)((u16*)Cout + row * N + colb);
            op[0] = p0.q; op[1] = p1.q;
        }
        asm volatile("s_waitcnt lgkmcnt(0)" ::: "memory");  // scratch reads done
    }
}

// ---------------------------------------------------------------------------
// Attention v4: swapped QK^T (S^T = mfma(K, Q)) so softmax over k is
// in-lane 16 + 2 quad-shfls per query group; P^T fragment has consecutive
// k in r -> packed ds_write_b64 into the same [m][k] LDS layout PV already
// consumes. Row-sum reciprocal redistributed via 64-float LDS array.
// DS-ops per block: ~248 -> ~96. Loads/PV/stores unchanged.
// ---------------------------------------------------------------------------
__global__ __launch_bounds__(64) void attn_kernel(
    const u16* __restrict__ qkv, const float* __restrict__ biasT,
    u16* __restrict__ O)
{
    __shared__ __align__(16) u16 Ps[64 * 72];   // P[m][k] bf16, 9216 B
    __shared__ __align__(16) u16 Vts[32 * 72];  // V^T[d][k], 4608 B
    __shared__ __align__(16) float rsumS[64];   // 1/rowsum per query m

    const int wid = blockIdx.x >> 4;
    const int h   = blockIdx.x & 15;
    const int b   = wid >> 6;
    const int wy  = (wid >> 3) & 7;
    const int wx  = wid & 7;
    const int cls = ((wy == 7) ? 2 : 0) + ((wx == 7) ? 1 : 0);
    const int lane = threadIdx.x;
    const int quad = lane >> 4, l16 = lane & 15;

    auto tokOf = [&](int m) -> size_t {
        int tt = m < 49 ? m : 48;
        int ty = tt / 7, tx = tt - ty * 7;
        int ho = wy * 7 + ty + 3; if (ho >= 56) ho -= 56;
        int wo = wx * 7 + tx + 3; if (wo >= 56) wo -= 56;
        return ((size_t)b * 56 + ho) * 56 + wo;
    };

    // ---- V gather -> Vts[dim][token] ----
    {
        size_t tok = tokOf(lane);
        const uint4* vs = (const uint4*)(qkv + tok * 1536 + 1024 + h * 32);
        union { uint4 u4[4]; u16 s[32]; } vb;
        vb.u4[0] = vs[0]; vb.u4[1] = vs[1]; vb.u4[2] = vs[2]; vb.u4[3] = vs[3];
#pragma unroll
        for (int d = 0; d < 32; d++) Vts[d * 72 + lane] = vb.s[d];
    }

    // ---- Q/K fragments directly from global ----
    bf16x8 aq[4], bk[4];
#pragma unroll
    for (int i = 0; i < 4; i++) {
        size_t tok = tokOf(i * 16 + l16);
        const u16* base = qkv + tok * 1536 + h * 32 + quad * 8;
        aq[i] = *(const bf16x8*)base;
        bk[i] = *(const bf16x8*)(base + 512);
    }

    const f32x4 fz = {0.f, 0.f, 0.f, 0.f};

    // ---- S^T = K·Q^T (swapped): acc[ki][nj][r] = S[m=nj*16+l16][k=ki*16+quad*4+r]
    f32x4 acc[4][4];
#pragma unroll
    for (int ki = 0; ki < 4; ki++)
#pragma unroll
        for (int nj = 0; nj < 4; nj++)
            acc[ki][nj] = __builtin_amdgcn_mfma_f32_16x16x32_bf16(
                bk[ki], aq[nj], fz, 0, 0, 0);

    // ---- s = S*scale + biasT(+mask,+pad) ----
    {
        const float scale = 0.17677669529663687f;  // 1/sqrt(32)
        const float* bp = biasT + (size_t)(cls * 16 + h) * 4096;
#pragma unroll
        for (int ki = 0; ki < 4; ki++)
#pragma unroll
            for (int nj = 0; nj < 4; nj++) {
                float4 bvv = ((const float4*)bp)[((ki * 4 + nj) * 4 + quad) * 16 + l16];
                const float* bvp = &bvv.x;
#pragma unroll
                for (int r = 0; r < 4; r++)
                    acc[ki][nj][r] = acc[ki][nj][r] * scale + bvp[r];
            }
    }

    // ---- softmax over k: 16 in-lane values + 2 quad-shfls per m-group ----
#pragma unroll
    for (int nj = 0; nj < 4; nj++) {
        float mx = acc[0][nj][0];
#pragma unroll
        for (int ki = 0; ki < 4; ki++)
#pragma unroll
            for (int r = 0; r < 4; r++)
                mx = fmaxf(mx, acc[ki][nj][r]);
        mx = fmaxf(mx, __shfl_xor(mx, 16, 64));
        mx = fmaxf(mx, __shfl_xor(mx, 32, 64));
        float s = 0.f;
#pragma unroll
        for (int ki = 0; ki < 4; ki++)
#pragma unroll
            for (int r = 0; r < 4; r++) {
                float e = __expf(acc[ki][nj][r] - mx);
                acc[ki][nj][r] = e;
                s += e;
            }
        s += __shfl_xor(s, 16, 64);
        s += __shfl_xor(s, 32, 64);
        if (quad == 0) rsumS[nj * 16 + l16] = __builtin_amdgcn_rcpf(s);
    }

    // ---- P^T frag -> Ps[m][k]: r is consecutive k, pack 4 bf16 per b64 ----
#pragma unroll
    for (int ki = 0; ki < 4; ki++)
#pragma unroll
        for (int nj = 0; nj < 4; nj++) {
            union { u16 s4[4]; uint2 v; } pk;
            pk.s4[0] = f2bf(acc[ki][nj][0]);
            pk.s4[1] = f2bf(acc[ki][nj][1]);
            pk.s4[2] = f2bf(acc[ki][nj][2]);
            pk.s4[3] = f2bf(acc[ki][nj][3]);
            *(uint2*)(Ps + (nj * 16 + l16) * 72 + ki * 16 + quad * 4) = pk.v;
        }
    __syncthreads();

    // ---- O = P V (4x2 tiles, K=64 -> 2 MFMA steps), normalized store ----
#pragma unroll
    for (int mi = 0; mi < 4; mi++) {
        f32x4 c0 = fz, c1 = fz;
#pragma unroll
        for (int ks = 0; ks < 2; ks++) {
            bf16x8 a = *(const bf16x8*)(Ps + (mi * 16 + l16) * 72 + ks * 32 + quad * 8);
            bf16x8 b0 = *(const bf16x8*)(Vts + l16 * 72 + ks * 32 + quad * 8);
            bf16x8 b1 = *(const bf16x8*)(Vts + (16 + l16) * 72 + ks * 32 + quad * 8);
            c0 = __builtin_amdgcn_mfma_f32_16x16x32_bf16(a, b0, c0, 0, 0, 0);
            c1 = __builtin_amdgcn_mfma_f32_16x16x32_bf16(a, b1, c1, 0, 0, 0);
        }
        f32x4 rv = *(const f32x4*)(rsumS + mi * 16 + quad * 4);
#pragma unroll
        for (int r = 0; r < 4; r++) {
            int m = mi * 16 + quad * 4 + r;
            if (m < 49) {
                int ty = m / 7, tx = m - ty * 7;
                int ho = wy * 7 + ty + 3; if (ho >= 56) ho -= 56;
                int wo = wx * 7 + tx + 3; if (wo >= 56) wo -= 56;
                size_t tok = ((size_t)b * 56 + ho) * 56 + wo;
                u16* op = O + tok * 512 + h * 32 + l16;
                op[0]  = f2bf(c0[r] * rv[r]);
                op[16] = f2bf(c1[r] * rv[r]);
            }
        }
    }
}

// ---------------------------------------------------------------------------
extern "C" void kernel_launch(void* const* d_in, const int* in_sizes, int n_in,
                              void* d_out, int out_size, void* d_ws, size_t ws_size,
                              hipStream_t stream)
{
    const float* x      = (const float*)d_in[0];
    const float* qkv_w  = (const float*)d_in[1];
    const float* qkv_b  = (const float*)d_in[2];
    const float* proj_w = (const float*)d_in[3];
    const float* proj_b = (const float*)d_in[4];
    const float* table  = (const float*)d_in[5];
    float* out = (float*)d_out;

    const int M  = 16 * 56 * 56;  // 50176 tokens
    const int Cd = 512, C3 = 1536;

    char* ws = (char*)d_ws;
    u16* QKV  = (u16*)ws;                                 // M*1536 bf16
    u16* Xb   = (u16*)(ws + (size_t)M * C3 * 2);          // M*512 bf16 (= Obuf)
    u16* Obuf = Xb;                                       // reused after gemm1
    u16* Wt1  = (u16*)(ws + (size_t)M * C3 * 2 + (size_t)M * Cd * 2);
    u16* Wt2  = Wt1 + (size_t)C3 * Cd;
    float* biasT = (float*)Wt1;  // 1 MB, aliases Wt1 (dead after gemm1)

    // merged cvt + both weight transposes (1 launch instead of 3)
    prep_kernel<<<dim3(4160), 1024, 0, stream>>>(x, Xb, qkv_w, Wt1, proj_w, Wt2);

    // QKV = Xb @ qkv_w + qkv_b   (grid 196*6 = 1176, %8==0)
    gemm256<false><<<dim3((M / 256) * (C3 / 256)), 512, 0, stream>>>(
        Xb, Wt1, qkv_b, nullptr, QKV, M, C3, Cd, C3 / 256);

    // transposed bias+mask tables (into Wt1's space — Wt1 dead now)
    build_bias<<<dim3(64), 64, 0, stream>>>(table, biasT);

    // windowed attention (shift + partition + reverse fused)
    attn_kernel<<<dim3(1024 * 16), 64, 0, stream>>>(QKV, biasT, Obuf);

    // out = Obuf @ proj_w + proj_b + x   (grid 196*2 = 392, %8==0)
    gemm256<true><<<dim3((M / 256) * (Cd / 256)), 512, 0, stream>>>(
        Obuf, Wt2, proj_b, x, out, M, Cd, Cd, Cd / 256);
}